// Round 13
// baseline (108.082 us; speedup 1.0000x reference)
//
#include <hip/hip_runtime.h>
#include <math.h>

#define BB 64
#define TT 8192
#define DD 128
#define RPT 64                   // rows per tile
#define NT 8                     // tiles per block
#define RPBLK (RPT * NT)         // 512 rows per block
#define NBLK (BB * TT / RPBLK)   // 1024 blocks
#define BPB (TT / RPBLK)         // 16 blocks per batch row

typedef float f32x4 __attribute__((ext_vector_type(4)));
typedef __bf16 bf16x4 __attribute__((ext_vector_type(4)));
typedef __bf16 bf16x8 __attribute__((ext_vector_type(8)));

__device__ __forceinline__ float fast_tanh(float x) {
    float t = __expf(2.f * x);
    return 1.f - 2.f * __builtin_amdgcn_rcpf(t + 1.f);
}

// u = 32-bit word holding two bf16: low 16 bits = element i, high = element i+1
__device__ __forceinline__ float bf_at_lo16(unsigned u) { return __uint_as_float(u << 16); }
__device__ __forceinline__ float bf_at_hi16(unsigned u) { return __uint_as_float(u & 0xffff0000u); }

// ---------------------------------------------------------------------------
// Kernel 0: V_w f32 -> bf16, PRE-SWIZZLED in ws: (r,c) -> r*128 + (c^((r&7)<<3))
// ---------------------------------------------------------------------------
__global__ __launch_bounds__(256) void convw_kernel(const float* __restrict__ Vw,
                                                    __bf16* __restrict__ Vw_bf) {
    const int i = blockIdx.x * 256 + threadIdx.x; // 0 .. 16383
    const int r = i >> 7, cidx = i & 127;
    Vw_bf[r * DD + (cidx ^ ((r & 7) << 3))] = (__bf16)Vw[i];
}

// ---------------------------------------------------------------------------
// Kernel 1: fkp[b,o] = dot(Wa_w[o,:], h_tm1[b,:]) + Wa_b[o]
// ---------------------------------------------------------------------------
__global__ __launch_bounds__(DD) void fkprime_kernel(
    const float* __restrict__ Waw, const float* __restrict__ Wab,
    const float* __restrict__ h_tm1, float* __restrict__ fkp) {
    const int b = blockIdx.x;
    const int o = threadIdx.x;
    const float* __restrict__ w = Waw + o * DD;
    const float* __restrict__ h = h_tm1 + b * DD;
    float a0 = 0.f, a1 = 0.f, a2 = 0.f, a3 = 0.f;
#pragma unroll
    for (int d = 0; d < DD; d += 4) {
        float4 w4 = *reinterpret_cast<const float4*>(w + d);
        a0 = fmaf(w4.x, h[d + 0], a0);
        a1 = fmaf(w4.y, h[d + 1], a1);
        a2 = fmaf(w4.z, h[d + 2], a2);
        a3 = fmaf(w4.w, h[d + 3], a3);
    }
    fkp[b * DD + o] = (a0 + a1) + (a2 + a3) + Wab[o];
}

// ---------------------------------------------------------------------------
// Kernel 2: fused scores + e' + z-partial. Per-wave dataflow: each wave owns
// 16 rows of each tile (stage/GEMM/z on its own rows) -> NO in-loop barriers.
// Prefetch pinned early via sched_barrier(0). Single H buffer, 3 blocks/CU.
// ---------------------------------------------------------------------------
__global__ __launch_bounds__(256, 3) void beta_z_kernel(
    const float* __restrict__ H, const __bf16* __restrict__ Vw_bf,
    const float* __restrict__ Vb, const float* __restrict__ fkp,
    const float* __restrict__ vvec, const float* __restrict__ cptr,
    const int* __restrict__ mask,
    float* __restrict__ eout,      // d_out beta region (e' before normalize)
    float* __restrict__ zpart) {   // [NBLK][DD]
    const int tid  = threadIdx.x;
    const int wv   = tid >> 6;
    const int lane = tid & 63;
    const int cl   = lane & 15;
    const int kg   = lane >> 4;
    const int base_row = blockIdx.x * RPBLK;
    const int b    = base_row >> 13; // 512 | 8192 so block is one b

    __shared__ short s_vw[DD * DD];    // 32 KB swizzled bf16 V_w
    __shared__ short s_h[RPT * DD];    // 16 KB swizzled bf16 H tile (single buf)
    __shared__ float s_z[4][DD];       // 2 KB

    // ---- prologue: V_w via global_load_lds (ws copy pre-swizzled) ----
    {
        const char* __restrict__ wg = (const char*)Vw_bf;
#pragma unroll
        for (int i = 0; i < 8; ++i) {
            __builtin_amdgcn_global_load_lds(
                (const void*)(wg + i * 4096 + wv * 1024 + lane * 16),
                (void*)((char*)s_vw + i * 4096 + wv * 1024), 16, 0, 0);
        }
    }
    // ---- stage tile 0, own 16 rows (contiguous 8 KB, coalesced) ----
    float4 hreg[8];
    {
        const float4* __restrict__ H4 =
            reinterpret_cast<const float4*>(H + (size_t)(base_row + wv * 16) * DD);
#pragma unroll
        for (int i = 0; i < 8; ++i) hreg[i] = H4[i * 64 + lane];
#pragma unroll
        for (int i = 0; i < 8; ++i) {
            bf16x4 r;
            r[0] = (__bf16)hreg[i].x; r[1] = (__bf16)hreg[i].y;
            r[2] = (__bf16)hreg[i].z; r[3] = (__bf16)hreg[i].w;
            const int off = wv * 4096 + (i * 64 + lane) * 8; // byte in 16 KB tile
            const int row = off >> 8;                        // 256 B per row
            *reinterpret_cast<bf16x4*>((char*)s_h + (off ^ ((row & 7) << 4))) = r;
        }
    }
    __syncthreads();  // drains V_w DMA (vmcnt) + all waves' tile-0 writes

    // hoisted per-lane epilogue constants
    const float cval = cptr[0];
    float biasv[8], vvv[8];
#pragma unroll
    for (int nt = 0; nt < 8; ++nt) {
        const int col = nt * 16 + cl;
        biasv[nt] = Vb[col] + fkp[b * DD + col];
        vvv[nt]   = vvec[col];
    }

    const int swzA = (cl & 7) << 4;  // (ra&7)<<4 with ra = wv*16+cl
    float za0 = 0.f, za1 = 0.f;      // z accumulators, d = 2*lane, 2*lane+1

    for (int t = 0; t < NT; ++t) {
        const int grow0 = base_row + t * RPT + wv * 16; // wave's first row

        // ---- prefetch next tile (own rows) + this tile's mask ----
        if (t + 1 < NT) {
            const float4* __restrict__ Hn = reinterpret_cast<const float4*>(
                H + (size_t)(grow0 + RPT) * DD);
#pragma unroll
            for (int i = 0; i < 8; ++i) hreg[i] = Hn[i * 64 + lane];
        }
        const float mfl = (float)mask[grow0 + cl]; // row (lane&15) of own 16
        __builtin_amdgcn_sched_barrier(0);         // pin loads above compute

        // ---- GEMM: own 16 rows x 128 cols ----
        f32x4 acc[8];
#pragma unroll
        for (int nt = 0; nt < 8; ++nt) acc[nt] = (f32x4){0.f, 0.f, 0.f, 0.f};
#pragma unroll
        for (int kk = 0; kk < 4; ++kk) {
            const int abyte = (wv * 16 + cl) * 256 + kk * 64 + kg * 16;
            bf16x8 af = *reinterpret_cast<const bf16x8*>((char*)s_h + (abyte ^ swzA));
#pragma unroll
            for (int nt = 0; nt < 8; ++nt) {
                const int rb    = nt * 16 + cl;
                const int bbyte = (rb * 256 + kk * 64 + kg * 16) ^ ((rb & 7) << 4);
                bf16x8 bfr = *reinterpret_cast<const bf16x8*>((const char*)s_vw + bbyte);
                acc[nt] = __builtin_amdgcn_mfma_f32_16x16x32_bf16(af, bfr, acc[nt], 0, 0, 0);
            }
        }

        // ---- epilogue: tanh, v-weighted row-sum, butterfly, e' ----
        float part[4] = {0.f, 0.f, 0.f, 0.f};
#pragma unroll
        for (int nt = 0; nt < 8; ++nt) {
#pragma unroll
            for (int j = 0; j < 4; ++j)
                part[j] = fmaf(fast_tanh(acc[nt][j] + biasv[nt]), vvv[nt], part[j]);
        }
#pragma unroll
        for (int off = 1; off < 16; off <<= 1) {
#pragma unroll
            for (int j = 0; j < 4; ++j) part[j] += __shfl_xor(part[j], off);
        }
        // ep for rows kg*4+j, valid in ALL lanes of quadrant kg
        float epj[4];
#pragma unroll
        for (int j = 0; j < 4; ++j) {
            const float mv = __shfl(mfl, kg * 4 + j);       // mask of that row
            const float x  = fminf(fmaxf(cval + part[j], -15.f), 15.f);
            epj[j] = __expf(x * mv - 15.f) * mv;
        }
        if (cl == 0) {
#pragma unroll
            for (int j = 0; j < 4; ++j) eout[grow0 + kg * 4 + j] = epj[j];
        }

        // ---- z-accumulate own 16 rows (ep via broadcast shfl) ----
#pragma unroll
        for (int r = 0; r < 16; ++r) {
            const float epr = __shfl(epj[r & 3], (r >> 2) << 4);
            const unsigned hv = *reinterpret_cast<const unsigned*>(
                (char*)s_h + (((wv * 16 + r) * 256 + lane * 4) ^ ((r & 7) << 4)));
            za0 = fmaf(epr, bf_at_lo16(hv), za0);  // d = 2*lane
            za1 = fmaf(epr, bf_at_hi16(hv), za1);  // d = 2*lane+1
        }

        // ---- write next tile into own rows (same-wave DS order is safe) ----
        if (t + 1 < NT) {
#pragma unroll
            for (int i = 0; i < 8; ++i) {
                bf16x4 r;
                r[0] = (__bf16)hreg[i].x; r[1] = (__bf16)hreg[i].y;
                r[2] = (__bf16)hreg[i].z; r[3] = (__bf16)hreg[i].w;
                const int off = wv * 4096 + (i * 64 + lane) * 8;
                const int row = off >> 8;
                *reinterpret_cast<bf16x4*>((char*)s_h + (off ^ ((row & 7) << 4))) = r;
            }
        }
    }

    // ---- final z-partial combine (one barrier) ----
    s_z[wv][2 * lane]     = za0;
    s_z[wv][2 * lane + 1] = za1;
    __syncthreads();
    if (tid < DD) {
        zpart[(size_t)blockIdx.x * DD + tid] =
            (s_z[0][tid] + s_z[1][tid]) + (s_z[2][tid] + s_z[3][tid]);
    }
}

// ---------------------------------------------------------------------------
// Kernel 3: per-b denom = sum(e') + 1e-6 * e^{gmax-15}; normalize beta in place.
// e^{gmax-15} = any_masked ? max(max e', e^-15) : max e'
// ---------------------------------------------------------------------------
__global__ __launch_bounds__(256) void denom_kernel(
    float* __restrict__ eout, const int* __restrict__ mask,
    float* __restrict__ denom) {
    const int b = blockIdx.x, tid = threadIdx.x;
    float* __restrict__ e = eout + (size_t)b * TT;
    const int* __restrict__ mrow = mask + (size_t)b * TT;
    __shared__ float sE[256], sM[256];
    __shared__ int sA[256];

    float E = 0.f, M = 0.f;
    int any0 = 0;
    for (int t = tid; t < TT; t += 256) {
        float ep = e[t];
        E += ep;
        M = fmaxf(M, ep);
        any0 |= (mrow[t] == 0);
    }
    sE[tid] = E; sM[tid] = M; sA[tid] = any0;
    __syncthreads();
    for (int s = 128; s > 0; s >>= 1) {
        if (tid < s) {
            sE[tid] += sE[tid + s];
            sM[tid] = fmaxf(sM[tid], sM[tid + s]);
            sA[tid] |= sA[tid + s];
        }
        __syncthreads();
    }
    const float scale = sA[0] ? fmaxf(sM[0], 3.0590232e-7f /*e^-15*/) : sM[0];
    const float dn = sE[0] + 1e-6f * scale;
    if (tid == 0) denom[b] = dn;
    const float inv = 1.f / dn;
    for (int t = tid; t < TT; t += 256) e[t] *= inv;
}

// ---------------------------------------------------------------------------
// Kernel 4: z[b,d] = (sum_c zpart[b*BPB+c][d]) / denom[b]
// ---------------------------------------------------------------------------
__global__ __launch_bounds__(256) void zfinal_kernel(
    const float* __restrict__ zpart, const float* __restrict__ denom,
    float* __restrict__ out_z) {
    const int idx = blockIdx.x * 256 + threadIdx.x; // 0 .. B*D-1
    const int b = idx >> 7, d = idx & 127;
    const float* __restrict__ zp = zpart + (size_t)b * BPB * DD + d;
    float s = 0.f;
#pragma unroll
    for (int cc = 0; cc < BPB; ++cc) s += zp[cc * DD];
    out_z[idx] = s / denom[b];
}

// ---------------------------------------------------------------------------
extern "C" void kernel_launch(void* const* d_in, const int* in_sizes, int n_in,
                              void* d_out, int out_size, void* d_ws, size_t ws_size,
                              hipStream_t stream) {
    const float* H     = (const float*)d_in[0]; // [B,T,D] f32
    const int*   mask  = (const int*)d_in[1];   // [B,T] int32
    const float* h_tm1 = (const float*)d_in[2]; // [B,D] f32
    const float* V_w   = (const float*)d_in[3]; // [D,D] f32
    const float* V_b   = (const float*)d_in[4]; // [D] f32
    const float* Wa_w  = (const float*)d_in[5]; // [D,D] f32
    const float* Wa_b  = (const float*)d_in[6]; // [D] f32
    const float* v     = (const float*)d_in[7]; // [D] f32
    const float* c     = (const float*)d_in[8]; // [1] f32

    float* out_z    = (float*)d_out;           // B*D f32
    float* out_beta = (float*)d_out + BB * DD; // B*T f32

    float* ws     = (float*)d_ws;
    float* fkp    = ws;                       // B*D     =   8192 f32
    float* zpart  = fkp + BB * DD;            // NBLK*DD = 131072 f32
    float* denom  = zpart + NBLK * DD;        // BB      =     64 f32
    __bf16* Vw_bf = (__bf16*)(denom + BB);    // D*D bf16 (pre-swizzled)

    convw_kernel<<<(DD * DD) / 256, 256, 0, stream>>>(V_w, Vw_bf);
    fkprime_kernel<<<BB, DD, 0, stream>>>(Wa_w, Wa_b, h_tm1, fkp);
    beta_z_kernel<<<NBLK, 256, 0, stream>>>(H, Vw_bf, V_b, fkp, v, c, mask,
                                            out_beta, zpart);
    denom_kernel<<<BB, 256, 0, stream>>>(out_beta, mask, denom);
    zfinal_kernel<<<(BB * DD) / 256, 256, 0, stream>>>(zpart, denom, out_z);
}

// Round 14
// 95.737 us; speedup vs baseline: 1.1289x; 1.1289x over previous
//
#include <hip/hip_runtime.h>
#include <math.h>

#define BB 64
#define TT 8192
#define DD 128
#define RPT 64                   // rows per tile
#define NT 8                     // tiles per block
#define RPBLK (RPT * NT)         // 512 rows per block
#define NBLK (BB * TT / RPBLK)   // 1024 blocks
#define BPB (TT / RPBLK)         // 16 blocks per batch row

typedef float f32x4 __attribute__((ext_vector_type(4)));
typedef __bf16 bf16x8 __attribute__((ext_vector_type(8)));

__device__ __forceinline__ float fast_tanh(float x) {
    float t = __expf(2.f * x);
    return 1.f - 2.f * __builtin_amdgcn_rcpf(t + 1.f);
}

__device__ __forceinline__ bf16x8 cvt8(f32x4 a, f32x4 b) {
    bf16x8 r;
    r[0] = (__bf16)a[0]; r[1] = (__bf16)a[1]; r[2] = (__bf16)a[2]; r[3] = (__bf16)a[3];
    r[4] = (__bf16)b[0]; r[5] = (__bf16)b[1]; r[6] = (__bf16)b[2]; r[7] = (__bf16)b[3];
    return r;
}

// ---------------------------------------------------------------------------
// Kernel 0: V_w f32 -> bf16, PRE-SWIZZLED in ws: (r,c) -> r*128 + (c^((r&7)<<3))
// ---------------------------------------------------------------------------
__global__ __launch_bounds__(256) void convw_kernel(const float* __restrict__ Vw,
                                                    __bf16* __restrict__ Vw_bf) {
    const int i = blockIdx.x * 256 + threadIdx.x; // 0 .. 16383
    const int r = i >> 7, cidx = i & 127;
    Vw_bf[r * DD + (cidx ^ ((r & 7) << 3))] = (__bf16)Vw[i];
}

// ---------------------------------------------------------------------------
// Kernel 1: fkp[b,o] = dot(Wa_w[o,:], h_tm1[b,:]) + Wa_b[o]
// ---------------------------------------------------------------------------
__global__ __launch_bounds__(DD) void fkprime_kernel(
    const float* __restrict__ Waw, const float* __restrict__ Wab,
    const float* __restrict__ h_tm1, float* __restrict__ fkp) {
    const int b = blockIdx.x;
    const int o = threadIdx.x;
    const float* __restrict__ w = Waw + o * DD;
    const float* __restrict__ h = h_tm1 + b * DD;
    float a0 = 0.f, a1 = 0.f, a2 = 0.f, a3 = 0.f;
#pragma unroll
    for (int d = 0; d < DD; d += 4) {
        float4 w4 = *reinterpret_cast<const float4*>(w + d);
        a0 = fmaf(w4.x, h[d + 0], a0);
        a1 = fmaf(w4.y, h[d + 1], a1);
        a2 = fmaf(w4.z, h[d + 2], a2);
        a3 = fmaf(w4.w, h[d + 3], a3);
    }
    fkp[b * DD + o] = (a0 + a1) + (a2 + a3) + Wab[o];
}

// ---------------------------------------------------------------------------
// Kernel 2: fused scores + e' + z. H tile f32 in LDS via global_load_lds with
// PRE-SWIZZLED per-lane SOURCE (linear LDS dest); z computed from the f32
// A-values in registers -> s_h has a single reader -> single buffer, no
// in-loop barriers, per-wave vmcnt(0) only. 2 blocks/CU (66 KB LDS).
// ---------------------------------------------------------------------------
__global__ __launch_bounds__(256, 2) void beta_z_kernel(
    const float* __restrict__ H, const __bf16* __restrict__ Vw_bf,
    const float* __restrict__ Vb, const float* __restrict__ fkp,
    const float* __restrict__ vvec, const float* __restrict__ cptr,
    const int* __restrict__ mask,
    float* __restrict__ eout,      // d_out beta region (e' before normalize)
    float* __restrict__ zpart) {   // [NBLK][DD]
    const int tid  = threadIdx.x;
    const int wv   = tid >> 6;
    const int lane = tid & 63;
    const int cl   = lane & 15;
    const int kg   = lane >> 4;
    const int base_row = blockIdx.x * RPBLK;
    const int b    = base_row >> 13; // 512 | 8192 so block is one b

    __shared__ __align__(16) char s_vw[DD * DD * 2];  // 32 KB bf16 V_w (pre-swz)
    __shared__ __align__(16) char s_h[RPT * DD * 4];  // 32 KB f32 H tile (swz layout)
    __shared__ float s_z[4][DD];                      // 2 KB

    // ---- prologue: V_w DMA (linear; ws copy pre-swizzled) ----
    {
        const char* __restrict__ wg = (const char*)Vw_bf;
#pragma unroll
        for (int i = 0; i < 8; ++i) {
            __builtin_amdgcn_global_load_lds(
                (const void*)(wg + wv * 8192 + i * 1024 + lane * 16),
                (void*)(s_vw + wv * 8192 + i * 1024), 16, 0, 0);
        }
    }
    // ---- tile-0 H DMA: own 16 rows; source pre-swizzled per-lane ----
    {
        const char* __restrict__ hb =
            (const char*)H + (size_t)(base_row + wv * 16) * 512;
#pragma unroll
        for (int i = 0; i < 8; ++i) {
            const int off  = i * 1024 + lane * 16;   // within wave's 8 KB
            const int r16  = off >> 9;               // row within own 16
            __builtin_amdgcn_global_load_lds(
                (const void*)(hb + (off ^ ((r16 & 7) << 4))),
                (void*)(s_h + wv * 8192 + i * 1024), 16, 0, 0);
        }
    }
    __syncthreads();  // drains vmcnt; s_vw + tile0 ready

    // hoisted per-lane epilogue constants
    const float cval = cptr[0];
    float biasv[8], vvv[8];
#pragma unroll
    for (int nt = 0; nt < 8; ++nt) {
        const int col = nt * 16 + cl;
        biasv[nt] = Vb[col] + fkp[b * DD + col];
        vvv[nt]   = vvec[col];
    }

    const int ra   = wv * 16 + cl;
    const int swzA = (cl & 7) << 4;
    f32x4 zlo[4], zhi[4];            // z accumulators: d = kk*32+kg*8+{0..3,4..7}
#pragma unroll
    for (int kk = 0; kk < 4; ++kk) {
        zlo[kk] = (f32x4){0.f, 0.f, 0.f, 0.f};
        zhi[kk] = (f32x4){0.f, 0.f, 0.f, 0.f};
    }

    for (int t = 0; t < NT; ++t) {
        const int grow0 = base_row + t * RPT + wv * 16;
        const float mfl = (float)mask[grow0 + cl];

        // ---- A-frag reads (f32, 2-way banks) + cvt ----
        f32x4 alo[4], ahi[4];
        bf16x8 af[4];
#pragma unroll
        for (int kk = 0; kk < 4; ++kk) {
            const int abyte = ra * 512 + kk * 128 + kg * 32;
            alo[kk] = *reinterpret_cast<const f32x4*>(s_h + ((abyte)      ^ swzA));
            ahi[kk] = *reinterpret_cast<const f32x4*>(s_h + ((abyte + 16) ^ swzA));
            af[kk]  = cvt8(alo[kk], ahi[kk]);
        }
        __builtin_amdgcn_sched_barrier(0);  // keep DMA below the frag reads

        // ---- issue next tile's DMA (overlaps GEMM+epi+z; s_h free now) ----
        if (t + 1 < NT) {
            const char* __restrict__ hb =
                (const char*)H + (size_t)(grow0 + RPT) * 512;
#pragma unroll
            for (int i = 0; i < 8; ++i) {
                const int off = i * 1024 + lane * 16;
                const int r16 = off >> 9;
                __builtin_amdgcn_global_load_lds(
                    (const void*)(hb + (off ^ ((r16 & 7) << 4))),
                    (void*)(s_h + wv * 8192 + i * 1024), 16, 0, 0);
            }
        }

        // ---- GEMM: own 16 rows x 128 cols ----
        f32x4 acc[8];
#pragma unroll
        for (int nt = 0; nt < 8; ++nt) acc[nt] = (f32x4){0.f, 0.f, 0.f, 0.f};
#pragma unroll
        for (int kk = 0; kk < 4; ++kk) {
#pragma unroll
            for (int nt = 0; nt < 8; ++nt) {
                const int rb    = nt * 16 + cl;
                const int bbyte = (rb * 256 + kk * 64 + kg * 16) ^ ((rb & 7) << 4);
                bf16x8 bfr = *reinterpret_cast<const bf16x8*>(s_vw + bbyte);
                acc[nt] = __builtin_amdgcn_mfma_f32_16x16x32_bf16(af[kk], bfr, acc[nt], 0, 0, 0);
            }
        }

        // ---- epilogue: tanh, v-weighted row-sum, butterfly, e' ----
        float part[4] = {0.f, 0.f, 0.f, 0.f};
#pragma unroll
        for (int nt = 0; nt < 8; ++nt) {
#pragma unroll
            for (int j = 0; j < 4; ++j)
                part[j] = fmaf(fast_tanh(acc[nt][j] + biasv[nt]), vvv[nt], part[j]);
        }
#pragma unroll
        for (int off = 1; off < 16; off <<= 1) {
#pragma unroll
            for (int j = 0; j < 4; ++j) part[j] += __shfl_xor(part[j], off);
        }
        float epj[4];
#pragma unroll
        for (int j = 0; j < 4; ++j) {
            const float mv = __shfl(mfl, kg * 4 + j);
            const float x  = fminf(fmaxf(cval + part[j], -15.f), 15.f);
            epj[j] = __expf(x * mv - 15.f) * mv;
        }
        if (cl == 0) {
#pragma unroll
            for (int j = 0; j < 4; ++j) eout[grow0 + kg * 4 + j] = epj[j];
        }

        // ---- z: e' of OWN row (cl) x register f32 A-values ----
        float er0 = __shfl(epj[0], (cl >> 2) << 4);
        float er1 = __shfl(epj[1], (cl >> 2) << 4);
        float er2 = __shfl(epj[2], (cl >> 2) << 4);
        float er3 = __shfl(epj[3], (cl >> 2) << 4);
        const int sel = cl & 3;
        float e_cl = sel == 0 ? er0 : (sel == 1 ? er1 : (sel == 2 ? er2 : er3));
#pragma unroll
        for (int kk = 0; kk < 4; ++kk) {
#pragma unroll
            for (int j = 0; j < 4; ++j) {
                zlo[kk][j] = fmaf(e_cl, alo[kk][j], zlo[kk][j]);
                zhi[kk][j] = fmaf(e_cl, ahi[kk][j], zhi[kk][j]);
            }
        }

        // ---- wait own DMAs before next tile's frag reads ----
        if (t + 1 < NT) asm volatile("s_waitcnt vmcnt(0)" ::: "memory");
    }

    // ---- final cross-lane z reduce (sum over the 16 cl-lanes) ----
#pragma unroll
    for (int off = 1; off < 16; off <<= 1) {
#pragma unroll
        for (int kk = 0; kk < 4; ++kk) {
#pragma unroll
            for (int j = 0; j < 4; ++j) {
                zlo[kk][j] += __shfl_xor(zlo[kk][j], off);
                zhi[kk][j] += __shfl_xor(zhi[kk][j], off);
            }
        }
    }
    if (cl == 0) {
#pragma unroll
        for (int kk = 0; kk < 4; ++kk) {
#pragma unroll
            for (int j = 0; j < 4; ++j) {
                s_z[wv][kk * 32 + kg * 8 + j]     = zlo[kk][j];
                s_z[wv][kk * 32 + kg * 8 + 4 + j] = zhi[kk][j];
            }
        }
    }
    __syncthreads();
    if (tid < DD) {
        zpart[(size_t)blockIdx.x * DD + tid] =
            (s_z[0][tid] + s_z[1][tid]) + (s_z[2][tid] + s_z[3][tid]);
    }
}

// ---------------------------------------------------------------------------
// Kernel 3: per-b denom = sum(e') + 1e-6 * e^{gmax-15}; normalize beta in place.
// e^{gmax-15} = any_masked ? max(max e', e^-15) : max e'
// ---------------------------------------------------------------------------
__global__ __launch_bounds__(256) void denom_kernel(
    float* __restrict__ eout, const int* __restrict__ mask,
    float* __restrict__ denom) {
    const int b = blockIdx.x, tid = threadIdx.x;
    float* __restrict__ e = eout + (size_t)b * TT;
    const int* __restrict__ mrow = mask + (size_t)b * TT;
    __shared__ float sE[256], sM[256];
    __shared__ int sA[256];

    float E = 0.f, M = 0.f;
    int any0 = 0;
    for (int t = tid; t < TT; t += 256) {
        float ep = e[t];
        E += ep;
        M = fmaxf(M, ep);
        any0 |= (mrow[t] == 0);
    }
    sE[tid] = E; sM[tid] = M; sA[tid] = any0;
    __syncthreads();
    for (int s = 128; s > 0; s >>= 1) {
        if (tid < s) {
            sE[tid] += sE[tid + s];
            sM[tid] = fmaxf(sM[tid], sM[tid + s]);
            sA[tid] |= sA[tid + s];
        }
        __syncthreads();
    }
    const float scale = sA[0] ? fmaxf(sM[0], 3.0590232e-7f /*e^-15*/) : sM[0];
    const float dn = sE[0] + 1e-6f * scale;
    if (tid == 0) denom[b] = dn;
    const float inv = 1.f / dn;
    for (int t = tid; t < TT; t += 256) e[t] *= inv;
}

// ---------------------------------------------------------------------------
// Kernel 4: z[b,d] = (sum_c zpart[b*BPB+c][d]) / denom[b]
// ---------------------------------------------------------------------------
__global__ __launch_bounds__(256) void zfinal_kernel(
    const float* __restrict__ zpart, const float* __restrict__ denom,
    float* __restrict__ out_z) {
    const int idx = blockIdx.x * 256 + threadIdx.x; // 0 .. B*D-1
    const int b = idx >> 7, d = idx & 127;
    const float* __restrict__ zp = zpart + (size_t)b * BPB * DD + d;
    float s = 0.f;
#pragma unroll
    for (int cc = 0; cc < BPB; ++cc) s += zp[cc * DD];
    out_z[idx] = s / denom[b];
}

// ---------------------------------------------------------------------------
extern "C" void kernel_launch(void* const* d_in, const int* in_sizes, int n_in,
                              void* d_out, int out_size, void* d_ws, size_t ws_size,
                              hipStream_t stream) {
    const float* H     = (const float*)d_in[0]; // [B,T,D] f32
    const int*   mask  = (const int*)d_in[1];   // [B,T] int32
    const float* h_tm1 = (const float*)d_in[2]; // [B,D] f32
    const float* V_w   = (const float*)d_in[3]; // [D,D] f32
    const float* V_b   = (const float*)d_in[4]; // [D] f32
    const float* Wa_w  = (const float*)d_in[5]; // [D,D] f32
    const float* Wa_b  = (const float*)d_in[6]; // [D] f32
    const float* v     = (const float*)d_in[7]; // [D] f32
    const float* c     = (const float*)d_in[8]; // [1] f32

    float* out_z    = (float*)d_out;           // B*D f32
    float* out_beta = (float*)d_out + BB * DD; // B*T f32

    float* ws     = (float*)d_ws;
    float* fkp    = ws;                       // B*D     =   8192 f32
    float* zpart  = fkp + BB * DD;            // NBLK*DD = 131072 f32
    float* denom  = zpart + NBLK * DD;        // BB      =     64 f32
    __bf16* Vw_bf = (__bf16*)(denom + BB);    // D*D bf16 (pre-swizzled)

    convw_kernel<<<(DD * DD) / 256, 256, 0, stream>>>(V_w, Vw_bf);
    fkprime_kernel<<<BB, DD, 0, stream>>>(Wa_w, Wa_b, h_tm1, fkp);
    beta_z_kernel<<<NBLK, 256, 0, stream>>>(H, Vw_bf, V_b, fkp, v, c, mask,
                                            out_beta, zpart);
    denom_kernel<<<BB, 256, 0, stream>>>(out_beta, mask, denom);
    zfinal_kernel<<<(BB * DD) / 256, 256, 0, stream>>>(zpart, denom, out_z);
}